// Round 11
// baseline (153.408 us; speedup 1.0000x reference)
//
#include <hip/hip_runtime.h>
#include <hip/hip_bf16.h>

#define BATCH 2
#define SEQ 2048
#define EMBED 1024
#define HEADS 16
#define HD 64

typedef __attribute__((ext_vector_type(8))) short short8;
typedef __attribute__((ext_vector_type(4))) float f32x4;
typedef __attribute__((ext_vector_type(16))) float f32x16;
typedef __attribute__((ext_vector_type(4))) int i32x4;
typedef unsigned short u16;

// log2-domain softmax constants: scale' = 0.125*log2(e); mask' = -1e9*log2(e)
#define C2F 0.18033688f
#define NEGL -1442695040.0f

__device__ __forceinline__ u16 f2bf(float x){
  unsigned u = __builtin_bit_cast(unsigned, x);
  u = (u + 0x7fffu + ((u >> 16) & 1u)) >> 16;
  return (u16)u;
}

// raw v_exp_f32: valid here because inputs are either normal-range or hugely
// negative (masked: flush-to-zero is exactly the reference fp32 behavior).
__device__ __forceinline__ float fexp2(float x){
  float r;
  asm("v_exp_f32 %0, %1" : "=v"(r) : "v"(x));
  return r;
}

// async global->LDS, 16B per lane; dest = wave-uniform base + lane*16
__device__ __forceinline__ void gload16(const u16* g, u16* l){
  __builtin_amdgcn_global_load_lds(
      (const __attribute__((address_space(1))) unsigned int*)g,
      (__attribute__((address_space(3))) unsigned int*)l, 16, 0, 0);
}

// ---------------- x fp32 -> bf16 (vectorized) ----------------
__global__ void k_cvt(const float* __restrict__ in, u16* __restrict__ out){
  int i = blockIdx.x * blockDim.x + threadIdx.x;
  float4 v = reinterpret_cast<const float4*>(in)[i];
  ushort4 o;
  o.x = f2bf(v.x); o.y = f2bf(v.y); o.z = f2bf(v.z); o.w = f2bf(v.w);
  reinterpret_cast<ushort4*>(out)[i] = o;
}

// ---------------- transpose [K][N] fp32 -> [N][K] bf16 ----------------
__global__ void k_transpose(const float* __restrict__ in, u16* __restrict__ out,
                            int K, int N){
  __shared__ float tile[32][33];
  int n0 = blockIdx.x * 32, k0 = blockIdx.y * 32;
  int tx = threadIdx.x, ty = threadIdx.y;   // block (32,8)
  #pragma unroll
  for (int i = 0; i < 32; i += 8)
    tile[ty + i][tx] = in[(size_t)(k0 + ty + i) * N + n0 + tx];
  __syncthreads();
  #pragma unroll
  for (int i = 0; i < 32; i += 8)
    out[(size_t)(n0 + ty + i) * K + k0 + tx] = f2bf(tile[tx][ty + i]);
}

// ---------------- GEMM1 (m97 structure): qkv = x@Wqkv + b, scatter Q/K/Vt ----
// 128x128 tile, BK=32, 4 waves (2x2), wave tile 64x64.
__global__ __launch_bounds__(256) void k_gemm_qkv(
    const u16* __restrict__ A, const u16* __restrict__ Bt,
    const float* __restrict__ bias,
    u16* __restrict__ qb, u16* __restrict__ kbf, u16* __restrict__ vt)
{
  const int K = 1024;
  __shared__ __align__(16) u16 As[128*32];
  __shared__ __align__(16) u16 Bs[128*32];
  int t = threadIdx.x;
  int wave = t >> 6, lane = t & 63;
  int g = lane >> 4, c = lane & 15;
  int wr = wave >> 1, wc = wave & 1;
  int mb = blockIdx.y * 128, nb = blockIdx.x * 128;

  const u16* ga = A  + (size_t)(mb + wave*32 + (lane>>2)) * K + (lane&3)*8;
  const u16* gb = Bt + (size_t)(nb + wave*32 + (lane>>2)) * K + (lane&3)*8;
  u16* la = &As[wave*1024];
  u16* lb = &Bs[wave*1024];

  f32x4 acc[4][4] = {};
  for (int k = 0; k < K; k += 32){
    gload16(ga + k,          la);
    gload16(ga + k + 16*K,   la + 512);
    gload16(gb + k,          lb);
    gload16(gb + k + 16*K,   lb + 512);
    __syncthreads();
    short8 af[4], bf[4];
    #pragma unroll
    for (int i = 0; i < 4; i++){
      af[i] = *reinterpret_cast<const short8*>(&As[(wr*64 + i*16 + c)*32 + 8*g]);
      bf[i] = *reinterpret_cast<const short8*>(&Bs[(wc*64 + i*16 + c)*32 + 8*g]);
    }
    #pragma unroll
    for (int i = 0; i < 4; i++)
      #pragma unroll
      for (int j = 0; j < 4; j++)
        acc[i][j] = __builtin_amdgcn_mfma_f32_16x16x32_bf16(af[i], bf[j], acc[i][j], 0, 0, 0);
    __syncthreads();
  }

  #pragma unroll
  for (int i = 0; i < 4; i++)
  #pragma unroll
  for (int j = 0; j < 4; j++)
  #pragma unroll
  for (int r = 0; r < 4; r++){
    int row = mb + wr*64 + i*16 + 4*g + r;
    int col = nb + wc*64 + j*16 + c;
    float v = acc[i][j][r] + bias[col];
    int h   = col / 192;
    int rem = col - h * 192;
    int sel = rem >> 6;
    int d   = rem & 63;
    int b   = row >> 11, s = row & 2047;
    u16 bv = f2bf(v);
    size_t base = (size_t)(b * HEADS + h);
    if (sel == 0)      qb [(base * SEQ + s) * HD + d] = bv;
    else if (sel == 1) kbf[(base * SEQ + s) * HD + d] = bv;
    else               vt [(base * HD + d) * SEQ + s] = bv;
  }
}

// ---------------- P-fragment pack: cvt_pk + permlane32_swap (T12) ----------------
template<int B>
__device__ __forceinline__ short8 pack_pa(const f32x16& p){
  unsigned X, Y, Z, W;
  asm("v_cvt_pk_bf16_f32 %0, %1, %2" : "=v"(X) : "v"(p[B+0]), "v"(p[B+1]));
  asm("v_cvt_pk_bf16_f32 %0, %1, %2" : "=v"(Y) : "v"(p[B+2]), "v"(p[B+3]));
  asm("v_cvt_pk_bf16_f32 %0, %1, %2" : "=v"(Z) : "v"(p[B+4]), "v"(p[B+5]));
  asm("v_cvt_pk_bf16_f32 %0, %1, %2" : "=v"(W) : "v"(p[B+6]), "v"(p[B+7]));
  asm("v_permlane32_swap_b32 %0, %1" : "+v"(X), "+v"(Z));
  asm("v_permlane32_swap_b32 %0, %1" : "+v"(Y), "+v"(W));
  i32x4 w = { (int)X, (int)Y, (int)Z, (int)W };
  return __builtin_bit_cast(short8, w);
}

// ---------------- fused anti-causal flash attention, swapped-QK 32x32 ----------
// Round-8 structure: 2048 blocks x 4 waves, kv-split interleaved, flash-combine
// in LDS. Kept from r9: shallow max tree + l cross-half sum hoisted out of the
// loop (one ds_bpermute/step removed). Reverted: permlane max-exchange (intra-asm
// hazard suspect, absmax 0.084) -> known-good __shfl_xor(.,32).
__global__ __launch_bounds__(256) void k_attn(
    const u16* __restrict__ qb, const u16* __restrict__ kbuf,
    const u16* __restrict__ vt, u16* __restrict__ vals)
{
  __shared__ __align__(16) u16 po[4][32][72];   // bf16 partial O, row-padded
  __shared__ float pmv[4][32];
  __shared__ float plv[4][32];

  int wave = threadIdx.x >> 6, lane = threadIdx.x & 63;
  int hi = lane >> 5, ln = lane & 31;
  // d0 -> (xcd, bh-group, q-tile): 4 heads' K/V (2MB) pinned per XCD L2.
  // heavy-first q-tile order: full-range tile (63) first, then ascending.
  int d0 = blockIdx.x;
  int x   = d0 & 7;
  int kk  = d0 >> 3;            // [0,256)
  int grp = kk >> 6;            // [0,4)
  int qr  = kk & 63;
  int qidx = (qr == 0) ? 63 : qr - 1;
  int bh  = x + 8 * grp;
  int qw  = qidx * 32;
  int qg  = qw + ln;
  const u16* Q  = qb   + (size_t)bh * SEQ * HD;
  const u16* Kp = kbuf + (size_t)bh * SEQ * HD;
  const u16* Vp = vt   + (size_t)bh * HD * SEQ;

  short8 qf[4];
  #pragma unroll
  for (int kc = 0; kc < 4; kc++)
    qf[kc] = *reinterpret_cast<const short8*>(Q + (size_t)qg * HD + kc*16 + 8*hi);

  f32x16 o0 = {}, o1 = {};
  float m = -INFINITY, l_part = 0.f;

  // anti-causal: rows need keys j > i; tile containing row S-1 needs all keys
  int kb0 = (qw + 32 >= SEQ) ? 0 : (qw & ~63);

  for (int kb = kb0 + wave*64; kb < SEQ; kb += 256){
    // ---- QK^T (swapped): S^T[key][q]; K loaded per-kc (low pressure) ----
    f32x16 s0 = {}, s1 = {};
    __builtin_amdgcn_s_setprio(1);
    #pragma unroll
    for (int kc = 0; kc < 4; kc++){
      short8 kf0 = *reinterpret_cast<const short8*>(Kp + (size_t)(kb      + ln) * HD + kc*16 + 8*hi);
      short8 kf1 = *reinterpret_cast<const short8*>(Kp + (size_t)(kb + 32 + ln) * HD + kc*16 + 8*hi);
      s0 = __builtin_amdgcn_mfma_f32_32x32x16_bf16(kf0, qf[kc], s0, 0, 0, 0);
      s1 = __builtin_amdgcn_mfma_f32_32x32x16_bf16(kf1, qf[kc], s1, 0, 0, 0);
    }
    __builtin_amdgcn_s_setprio(0);
    // ---- mask (rare, wave-uniform); unmasked path stays in raw domain ----
    bool mk = (kb <= qw + 31);
    if (mk){
      #pragma unroll
      for (int r = 0; r < 16; r++){
        int kv = kb + 4*hi + (r & 3) + 8*(r >> 2);
        s0[r] = s0[r]*C2F + ((kv      <= qg) ? NEGL : 0.f);
        s1[r] = s1[r]*C2F + ((kv + 32 <= qg) ? NEGL : 0.f);
      }
    }
    // ---- row max: shallow tree (8 temps) + one cross-half exchange ----
    float tt[8];
    #pragma unroll
    for (int r = 0; r < 8; r++)
      tt[r] = fmaxf(fmaxf(s0[r], s0[r+8]), fmaxf(s1[r], s1[r+8]));
    float ma = fmaxf(fmaxf(tt[0], tt[1]), fmaxf(tt[2], tt[3]));
    float mb2 = fmaxf(fmaxf(tt[4], tt[5]), fmaxf(tt[6], tt[7]));
    float pmx = fmaxf(ma, mb2);
    pmx = fmaxf(pmx, __shfl_xor(pmx, 32));
    if (!mk) pmx *= C2F;          // max commutes with positive scale
    // ---- defer-max rescale (wave-uniform, rare) ----
    if (__any(pmx > m + 8.0f)){
      float mn = fmaxf(m, pmx);
      float al = fexp2(m - mn);
      #pragma unroll
      for (int r = 0; r < 16; r++){
        float alr = __shfl(al, (r & 3) + 8*(r >> 2) + 4*hi);
        o0[r] *= alr; o1[r] *= alr;
      }
      l_part *= al;
      m = mn;
    }
    // ---- p = 2^(fma(s,a,-m)); per-lane partial sum (no exchange in loop) ----
    float negm = -m;
    float aa = mk ? 1.0f : C2F;
    float ps = 0.f;
    #pragma unroll
    for (int r = 0; r < 16; r++){
      s0[r] = fexp2(fmaf(s0[r], aa, negm));
      s1[r] = fexp2(fmaf(s1[r], aa, negm));
      ps += s0[r] + s1[r];
    }
    l_part += ps;
    // ---- pack P into A-frags, then V loads, then PV ----
    short8 pa00 = pack_pa<0>(s0), pa01 = pack_pa<8>(s0);
    short8 pa10 = pack_pa<0>(s1), pa11 = pack_pa<8>(s1);
    const u16* vr0 = Vp + (size_t)(ln)      * SEQ + kb + 8*hi;
    const u16* vr1 = Vp + (size_t)(32 + ln) * SEQ + kb + 8*hi;
    short8 vf;
    __builtin_amdgcn_s_setprio(1);
    vf = *reinterpret_cast<const short8*>(vr0);
    o0 = __builtin_amdgcn_mfma_f32_32x32x16_bf16(pa00, vf, o0, 0, 0, 0);
    vf = *reinterpret_cast<const short8*>(vr0 + 16);
    o0 = __builtin_amdgcn_mfma_f32_32x32x16_bf16(pa01, vf, o0, 0, 0, 0);
    vf = *reinterpret_cast<const short8*>(vr0 + 32);
    o0 = __builtin_amdgcn_mfma_f32_32x32x16_bf16(pa10, vf, o0, 0, 0, 0);
    vf = *reinterpret_cast<const short8*>(vr0 + 48);
    o0 = __builtin_amdgcn_mfma_f32_32x32x16_bf16(pa11, vf, o0, 0, 0, 0);
    vf = *reinterpret_cast<const short8*>(vr1);
    o1 = __builtin_amdgcn_mfma_f32_32x32x16_bf16(pa00, vf, o1, 0, 0, 0);
    vf = *reinterpret_cast<const short8*>(vr1 + 16);
    o1 = __builtin_amdgcn_mfma_f32_32x32x16_bf16(pa01, vf, o1, 0, 0, 0);
    vf = *reinterpret_cast<const short8*>(vr1 + 32);
    o1 = __builtin_amdgcn_mfma_f32_32x32x16_bf16(pa10, vf, o1, 0, 0, 0);
    vf = *reinterpret_cast<const short8*>(vr1 + 48);
    o1 = __builtin_amdgcn_mfma_f32_32x32x16_bf16(pa11, vf, o1, 0, 0, 0);
    __builtin_amdgcn_s_setprio(0);
  }

  // ---- complete l: one cross-half exchange after the loop ----
  float l = l_part + __shfl_xor(l_part, 32);

  // ---- write per-wave partial state to LDS (O in bf16) ----
  #pragma unroll
  for (int r = 0; r < 16; r++){
    int row = (r & 3) + 8*(r >> 2) + 4*hi;
    po[wave][row][ln]      = f2bf(o0[r]);
    po[wave][row][32 + ln] = f2bf(o1[r]);
  }
  if (hi == 0){ pmv[wave][ln] = m; plv[wave][ln] = l; }
  __syncthreads();

  // ---- flash-combine 4 partials; 256 threads cover 32 rows x 64 cols ----
  int t   = threadIdx.x;
  int row = t >> 3;
  int c8  = (t & 7) * 8;
  float m0 = pmv[0][row], m1 = pmv[1][row], m2 = pmv[2][row], m3 = pmv[3][row];
  float ms = fmaxf(fmaxf(m0, m1), fmaxf(m2, m3));
  float f0 = fexp2(m0 - ms), f1 = fexp2(m1 - ms);
  float f2 = fexp2(m2 - ms), f3 = fexp2(m3 - ms);
  float ls = plv[0][row]*f0 + plv[1][row]*f1 + plv[2][row]*f2 + plv[3][row]*f3;
  float inv = 1.0f / ls;
  f0 *= inv; f1 *= inv; f2 *= inv; f3 *= inv;
  int b = bh >> 4, h = bh & 15;
  u16 tmp[8];
  #pragma unroll
  for (int i = 0; i < 8; i += 4){
    ushort4 w0 = *reinterpret_cast<const ushort4*>(&po[0][row][c8 + i]);
    ushort4 w1 = *reinterpret_cast<const ushort4*>(&po[1][row][c8 + i]);
    ushort4 w2 = *reinterpret_cast<const ushort4*>(&po[2][row][c8 + i]);
    ushort4 w3 = *reinterpret_cast<const ushort4*>(&po[3][row][c8 + i]);
    const u16* p0 = (const u16*)&w0; const u16* p1 = (const u16*)&w1;
    const u16* p2 = (const u16*)&w2; const u16* p3 = (const u16*)&w3;
    #pragma unroll
    for (int j = 0; j < 4; j++){
      float v = __builtin_bit_cast(float, (unsigned)p0[j] << 16) * f0
              + __builtin_bit_cast(float, (unsigned)p1[j] << 16) * f1
              + __builtin_bit_cast(float, (unsigned)p2[j] << 16) * f2
              + __builtin_bit_cast(float, (unsigned)p3[j] << 16) * f3;
      tmp[i + j] = f2bf(v);
    }
  }
  u16* dst = vals + ((size_t)(b * SEQ + qw + row)) * EMBED + h * HD + c8;
  *reinterpret_cast<ushort4*>(dst)     = *reinterpret_cast<ushort4*>(&tmp[0]);
  *reinterpret_cast<ushort4*>(dst + 4) = *reinterpret_cast<ushort4*>(&tmp[4]);
}

// ---------------- GEMM2 (m97 structure): out = vals @ Wout + b ----------------
// 64x128 tile, BK=32, 4 waves (2x2), wave tile 32x64. Grid 512 blocks.
__global__ __launch_bounds__(256) void k_gemm_out(
    const u16* __restrict__ A, const u16* __restrict__ Bt,
    const float* __restrict__ bias, float* __restrict__ out)
{
  const int K = 1024;
  __shared__ __align__(16) u16 As[64*32];
  __shared__ __align__(16) u16 Bs[128*32];
  int t = threadIdx.x;
  int wave = t >> 6, lane = t & 63;
  int g = lane >> 4, c = lane & 15;
  int wr = wave >> 1, wc = wave & 1;
  int mb = blockIdx.y * 64, nb = blockIdx.x * 128;

  const u16* ga = A  + (size_t)(mb + wave*16 + (lane>>2)) * K + (lane&3)*8;
  const u16* gb = Bt + (size_t)(nb + wave*32 + (lane>>2)) * K + (lane&3)*8;
  u16* la = &As[wave*512];
  u16* lb = &Bs[wave*1024];

  f32x4 acc[2][4] = {};
  for (int k = 0; k < K; k += 32){
    gload16(ga + k,          la);
    gload16(gb + k,          lb);
    gload16(gb + k + 16*K,   lb + 512);
    __syncthreads();
    short8 af[2], bf[4];
    #pragma unroll
    for (int i = 0; i < 2; i++)
      af[i] = *reinterpret_cast<const short8*>(&As[(wr*32 + i*16 + c)*32 + 8*g]);
    #pragma unroll
    for (int j = 0; j < 4; j++)
      bf[j] = *reinterpret_cast<const short8*>(&Bs[(wc*64 + j*16 + c)*32 + 8*g]);
    #pragma unroll
    for (int i = 0; i < 2; i++)
      #pragma unroll
      for (int j = 0; j < 4; j++)
        acc[i][j] = __builtin_amdgcn_mfma_f32_16x16x32_bf16(af[i], bf[j], acc[i][j], 0, 0, 0);
    __syncthreads();
  }

  #pragma unroll
  for (int i = 0; i < 2; i++)
  #pragma unroll
  for (int j = 0; j < 4; j++)
  #pragma unroll
  for (int r = 0; r < 4; r++){
    int row = mb + wr*32 + i*16 + 4*g + r;
    int col = nb + wc*64 + j*16 + c;
    out[(size_t)row * EMBED + col] = acc[i][j][r] + bias[col];
  }
}

extern "C" void kernel_launch(void* const* d_in, const int* in_sizes, int n_in,
                              void* d_out, int out_size, void* d_ws, size_t ws_size,
                              hipStream_t stream){
  const float* x    = (const float*)d_in[0];
  const float* Wqkv = (const float*)d_in[1];
  const float* bqkv = (const float*)d_in[2];
  const float* Wout = (const float*)d_in[3];
  const float* bout = (const float*)d_in[4];
  float* out = (float*)d_out;

  char* ws = (char*)d_ws;
  u16* x_bf   = (u16*)(ws);                       // 8 MB
  u16* wqkv_t = (u16*)(ws + ( 8u << 20));         // 6 MB
  u16* wout_t = (u16*)(ws + (14u << 20));         // 2 MB
  u16* qbuf   = (u16*)(ws + (16u << 20));         // 8 MB
  u16* kbuf   = (u16*)(ws + (24u << 20));         // 8 MB
  u16* vtbuf  = (u16*)(ws + (32u << 20));         // 8 MB
  u16* vals   = (u16*)(ws + (40u << 20));         // 8 MB   (48 MB total)

  k_cvt<<<4096, 256, 0, stream>>>(x, x_bf);
  dim3 tb(32, 8);
  k_transpose<<<dim3(3072/32, 1024/32), tb, 0, stream>>>(Wqkv, wqkv_t, 1024, 3072);
  k_transpose<<<dim3(1024/32, 1024/32), tb, 0, stream>>>(Wout, wout_t, 1024, 1024);
  k_gemm_qkv<<<dim3(3072/128, 4096/128), 256, 0, stream>>>(x_bf, wqkv_t, bqkv, qbuf, kbuf, vtbuf);
  k_attn<<<2048, 256, 0, stream>>>(qbuf, kbuf, vtbuf, vals);
  k_gemm_out<<<dim3(1024/128, 4096/64), 256, 0, stream>>>(vals, wout_t, bout, out);
}

// Round 12
// 126.974 us; speedup vs baseline: 1.2082x; 1.2082x over previous
//
#include <hip/hip_runtime.h>
#include <hip/hip_bf16.h>

#define BATCH 2
#define SEQ 2048
#define EMBED 1024
#define HEADS 16
#define HD 64

typedef __attribute__((ext_vector_type(8))) short short8;
typedef __attribute__((ext_vector_type(4))) float f32x4;
typedef __attribute__((ext_vector_type(16))) float f32x16;
typedef __attribute__((ext_vector_type(4))) int i32x4;
typedef unsigned short u16;

// log2-domain softmax constants: scale' = 0.125*log2(e); mask' = -1e9*log2(e)
#define C2F 0.18033688f
#define NEGL -1442695040.0f

__device__ __forceinline__ u16 f2bf(float x){
  unsigned u = __builtin_bit_cast(unsigned, x);
  u = (u + 0x7fffu + ((u >> 16) & 1u)) >> 16;
  return (u16)u;
}

// raw v_exp_f32: valid here because inputs are either normal-range or hugely
// negative (masked: flush-to-zero is exactly the reference fp32 behavior).
__device__ __forceinline__ float fexp2(float x){
  float r;
  asm("v_exp_f32 %0, %1" : "=v"(r) : "v"(x));
  return r;
}

// async global->LDS, 16B per lane; dest = wave-uniform base + lane*16
__device__ __forceinline__ void gload16(const u16* g, u16* l){
  __builtin_amdgcn_global_load_lds(
      (const __attribute__((address_space(1))) unsigned int*)g,
      (__attribute__((address_space(3))) unsigned int*)l, 16, 0, 0);
}

// ---------------- x fp32 -> bf16 (vectorized) ----------------
__global__ void k_cvt(const float* __restrict__ in, u16* __restrict__ out){
  int i = blockIdx.x * blockDim.x + threadIdx.x;
  float4 v = reinterpret_cast<const float4*>(in)[i];
  ushort4 o;
  o.x = f2bf(v.x); o.y = f2bf(v.y); o.z = f2bf(v.z); o.w = f2bf(v.w);
  reinterpret_cast<ushort4*>(out)[i] = o;
}

// ---------------- transpose [K][N] fp32 -> [N][K] bf16 ----------------
__global__ void k_transpose(const float* __restrict__ in, u16* __restrict__ out,
                            int K, int N){
  __shared__ float tile[32][33];
  int n0 = blockIdx.x * 32, k0 = blockIdx.y * 32;
  int tx = threadIdx.x, ty = threadIdx.y;   // block (32,8)
  #pragma unroll
  for (int i = 0; i < 32; i += 8)
    tile[ty + i][tx] = in[(size_t)(k0 + ty + i) * N + n0 + tx];
  __syncthreads();
  #pragma unroll
  for (int i = 0; i < 32; i += 8)
    out[(size_t)(n0 + ty + i) * K + k0 + tx] = f2bf(tile[tx][ty + i]);
}

// ---------------- GEMM1 (m97 structure): qkv = x@Wqkv + b ----------------
// Q/K/V are scattered into MFMA-FRAGMENT order so k_attn's loads are
// base + lane*16B (perfectly coalesced):
//   Q,K (A/B row=lane&31, k=8*(lane>>5)+j): per (bh, s>>5, d>>4) 512-u16 tile,
//     lane=(s&31)|(((d>>3)&1)<<5), j=d&7.
//   V  (B col=lane&31=d&31):                per (bh, s>>4, d>>5) 512-u16 tile,
//     lane=(d&31)|(((s>>3)&1)<<5), j=s&7.
__global__ __launch_bounds__(256) void k_gemm_qkv(
    const u16* __restrict__ A, const u16* __restrict__ Bt,
    const float* __restrict__ bias,
    u16* __restrict__ qb, u16* __restrict__ kbf, u16* __restrict__ vt)
{
  const int K = 1024;
  __shared__ __align__(16) u16 As[128*32];
  __shared__ __align__(16) u16 Bs[128*32];
  int t = threadIdx.x;
  int wave = t >> 6, lane = t & 63;
  int g = lane >> 4, c = lane & 15;
  int wr = wave >> 1, wc = wave & 1;
  int mb = blockIdx.y * 128, nb = blockIdx.x * 128;

  const u16* ga = A  + (size_t)(mb + wave*32 + (lane>>2)) * K + (lane&3)*8;
  const u16* gb = Bt + (size_t)(nb + wave*32 + (lane>>2)) * K + (lane&3)*8;
  u16* la = &As[wave*1024];
  u16* lb = &Bs[wave*1024];

  f32x4 acc[4][4] = {};
  for (int k = 0; k < K; k += 32){
    gload16(ga + k,          la);
    gload16(ga + k + 16*K,   la + 512);
    gload16(gb + k,          lb);
    gload16(gb + k + 16*K,   lb + 512);
    __syncthreads();
    short8 af[4], bf[4];
    #pragma unroll
    for (int i = 0; i < 4; i++){
      af[i] = *reinterpret_cast<const short8*>(&As[(wr*64 + i*16 + c)*32 + 8*g]);
      bf[i] = *reinterpret_cast<const short8*>(&Bs[(wc*64 + i*16 + c)*32 + 8*g]);
    }
    #pragma unroll
    for (int i = 0; i < 4; i++)
      #pragma unroll
      for (int j = 0; j < 4; j++)
        acc[i][j] = __builtin_amdgcn_mfma_f32_16x16x32_bf16(af[i], bf[j], acc[i][j], 0, 0, 0);
    __syncthreads();
  }

  #pragma unroll
  for (int i = 0; i < 4; i++)
  #pragma unroll
  for (int j = 0; j < 4; j++)
  #pragma unroll
  for (int r = 0; r < 4; r++){
    int row = mb + wr*64 + i*16 + 4*g + r;
    int col = nb + wc*64 + j*16 + c;
    float v = acc[i][j][r] + bias[col];
    int h   = col / 192;
    int rem = col - h * 192;
    int sel = rem >> 6;
    int d   = rem & 63;
    int b   = row >> 11, s = row & 2047;
    u16 bv = f2bf(v);
    size_t base = (size_t)(b * HEADS + h);
    if (sel == 2){
      size_t off = (((base*128 + (s>>4))*2 + (d>>5))*64
                    + (size_t)((d&31)|(((s>>3)&1)<<5)))*8 + (s&7);
      vt[off] = bv;
    } else {
      size_t off = (((base*64 + (s>>5))*4 + (d>>4))*64
                    + (size_t)((s&31)|(((d>>3)&1)<<5)))*8 + (d&7);
      if (sel == 0) qb[off] = bv; else kbf[off] = bv;
    }
  }
}

// ---------------- P-fragment pack: cvt_pk + permlane32_swap (T12) ----------------
template<int B>
__device__ __forceinline__ short8 pack_pa(const f32x16& p){
  unsigned X, Y, Z, W;
  asm("v_cvt_pk_bf16_f32 %0, %1, %2" : "=v"(X) : "v"(p[B+0]), "v"(p[B+1]));
  asm("v_cvt_pk_bf16_f32 %0, %1, %2" : "=v"(Y) : "v"(p[B+2]), "v"(p[B+3]));
  asm("v_cvt_pk_bf16_f32 %0, %1, %2" : "=v"(Z) : "v"(p[B+4]), "v"(p[B+5]));
  asm("v_cvt_pk_bf16_f32 %0, %1, %2" : "=v"(W) : "v"(p[B+6]), "v"(p[B+7]));
  asm("v_permlane32_swap_b32 %0, %1" : "+v"(X), "+v"(Z));
  asm("v_permlane32_swap_b32 %0, %1" : "+v"(Y), "+v"(W));
  i32x4 w = { (int)X, (int)Y, (int)Z, (int)W };
  return __builtin_bit_cast(short8, w);
}

// ---------------- fused anti-causal flash attention, swapped-QK 32x32 ----------
// Round-10 structure; all Q/K/V global loads are now fragment-ordered:
// every hot-loop load is base + lane*16B (1KB coalesced per instruction).
__global__ __launch_bounds__(256) void k_attn(
    const u16* __restrict__ qb, const u16* __restrict__ kbuf,
    const u16* __restrict__ vt, u16* __restrict__ vals)
{
  __shared__ __align__(16) u16 po[4][32][72];   // bf16 partial O, row-padded
  __shared__ float pmv[4][32];
  __shared__ float plv[4][32];

  int wave = threadIdx.x >> 6, lane = threadIdx.x & 63;
  int hi = lane >> 5, ln = lane & 31;
  // d0 -> (xcd, bh-group, q-tile): 4 heads' K/V (2MB) pinned per XCD L2.
  // heavy-first q-tile order: full-range tile (63) first, then ascending.
  int d0 = blockIdx.x;
  int x   = d0 & 7;
  int kk  = d0 >> 3;            // [0,256)
  int grp = kk >> 6;            // [0,4)
  int qr  = kk & 63;
  int qidx = (qr == 0) ? 63 : qr - 1;
  int bh  = x + 8 * grp;
  int qw  = qidx * 32;
  int qg  = qw + ln;

  // fragment-space base pointers (each bh = 256 tiles x 512 u16 = 256KB)
  const u16* Qf = qb   + (size_t)bh*131072 + ((size_t)(qw>>5)*4)*512 + (size_t)lane*8;
  const u16* Kf = kbuf + (size_t)bh*131072 + (size_t)lane*8;
  const u16* Vf = vt   + (size_t)bh*131072 + (size_t)lane*8;

  short8 qf[4];
  #pragma unroll
  for (int kc = 0; kc < 4; kc++)
    qf[kc] = *reinterpret_cast<const short8*>(Qf + (size_t)kc*512);

  f32x16 o0 = {}, o1 = {};
  float m = -INFINITY, l_part = 0.f;

  // anti-causal: rows need keys j > i; tile containing row S-1 needs all keys
  int kb0 = (qw + 32 >= SEQ) ? 0 : (qw & ~63);

  for (int kb = kb0 + wave*64; kb < SEQ; kb += 256){
    // ---- QK^T (swapped): S^T[key][q]; fragment-ordered K loads ----
    int tk = (kb >> 5) * 4;
    f32x16 s0 = {}, s1 = {};
    __builtin_amdgcn_s_setprio(1);
    #pragma unroll
    for (int kc = 0; kc < 4; kc++){
      short8 kf0 = *reinterpret_cast<const short8*>(Kf + (size_t)(tk + kc)*512);
      short8 kf1 = *reinterpret_cast<const short8*>(Kf + (size_t)(tk + 4 + kc)*512);
      s0 = __builtin_amdgcn_mfma_f32_32x32x16_bf16(kf0, qf[kc], s0, 0, 0, 0);
      s1 = __builtin_amdgcn_mfma_f32_32x32x16_bf16(kf1, qf[kc], s1, 0, 0, 0);
    }
    __builtin_amdgcn_s_setprio(0);
    // ---- mask (rare, wave-uniform); unmasked path stays in raw domain ----
    bool mk = (kb <= qw + 31);
    if (mk){
      #pragma unroll
      for (int r = 0; r < 16; r++){
        int kv = kb + 4*hi + (r & 3) + 8*(r >> 2);
        s0[r] = s0[r]*C2F + ((kv      <= qg) ? NEGL : 0.f);
        s1[r] = s1[r]*C2F + ((kv + 32 <= qg) ? NEGL : 0.f);
      }
    }
    // ---- row max: shallow tree (8 temps) + one cross-half exchange ----
    float tt[8];
    #pragma unroll
    for (int r = 0; r < 8; r++)
      tt[r] = fmaxf(fmaxf(s0[r], s0[r+8]), fmaxf(s1[r], s1[r+8]));
    float ma = fmaxf(fmaxf(tt[0], tt[1]), fmaxf(tt[2], tt[3]));
    float mb2 = fmaxf(fmaxf(tt[4], tt[5]), fmaxf(tt[6], tt[7]));
    float pmx = fmaxf(ma, mb2);
    pmx = fmaxf(pmx, __shfl_xor(pmx, 32));
    if (!mk) pmx *= C2F;          // max commutes with positive scale
    // ---- defer-max rescale (wave-uniform, rare) ----
    if (__any(pmx > m + 8.0f)){
      float mn = fmaxf(m, pmx);
      float al = fexp2(m - mn);
      #pragma unroll
      for (int r = 0; r < 16; r++){
        float alr = __shfl(al, (r & 3) + 8*(r >> 2) + 4*hi);
        o0[r] *= alr; o1[r] *= alr;
      }
      l_part *= al;
      m = mn;
    }
    // ---- p = 2^(fma(s,a,-m)); per-lane partial sum (no exchange in loop) ----
    float negm = -m;
    float aa = mk ? 1.0f : C2F;
    float ps = 0.f;
    #pragma unroll
    for (int r = 0; r < 16; r++){
      s0[r] = fexp2(fmaf(s0[r], aa, negm));
      s1[r] = fexp2(fmaf(s1[r], aa, negm));
      ps += s0[r] + s1[r];
    }
    l_part += ps;
    // ---- pack P into A-frags, then fragment-ordered V loads, then PV ----
    short8 pa00 = pack_pa<0>(s0), pa01 = pack_pa<8>(s0);
    short8 pa10 = pack_pa<0>(s1), pa11 = pack_pa<8>(s1);
    int tv = (kb >> 4) * 2;
    short8 vf;
    __builtin_amdgcn_s_setprio(1);
    vf = *reinterpret_cast<const short8*>(Vf + (size_t)(tv + 0)*512);
    o0 = __builtin_amdgcn_mfma_f32_32x32x16_bf16(pa00, vf, o0, 0, 0, 0);
    vf = *reinterpret_cast<const short8*>(Vf + (size_t)(tv + 2)*512);
    o0 = __builtin_amdgcn_mfma_f32_32x32x16_bf16(pa01, vf, o0, 0, 0, 0);
    vf = *reinterpret_cast<const short8*>(Vf + (size_t)(tv + 4)*512);
    o0 = __builtin_amdgcn_mfma_f32_32x32x16_bf16(pa10, vf, o0, 0, 0, 0);
    vf = *reinterpret_cast<const short8*>(Vf + (size_t)(tv + 6)*512);
    o0 = __builtin_amdgcn_mfma_f32_32x32x16_bf16(pa11, vf, o0, 0, 0, 0);
    vf = *reinterpret_cast<const short8*>(Vf + (size_t)(tv + 1)*512);
    o1 = __builtin_amdgcn_mfma_f32_32x32x16_bf16(pa00, vf, o1, 0, 0, 0);
    vf = *reinterpret_cast<const short8*>(Vf + (size_t)(tv + 3)*512);
    o1 = __builtin_amdgcn_mfma_f32_32x32x16_bf16(pa01, vf, o1, 0, 0, 0);
    vf = *reinterpret_cast<const short8*>(Vf + (size_t)(tv + 5)*512);
    o1 = __builtin_amdgcn_mfma_f32_32x32x16_bf16(pa10, vf, o1, 0, 0, 0);
    vf = *reinterpret_cast<const short8*>(Vf + (size_t)(tv + 7)*512);
    o1 = __builtin_amdgcn_mfma_f32_32x32x16_bf16(pa11, vf, o1, 0, 0, 0);
    __builtin_amdgcn_s_setprio(0);
  }

  // ---- complete l: one cross-half exchange after the loop ----
  float l = l_part + __shfl_xor(l_part, 32);

  // ---- write per-wave partial state to LDS (O in bf16) ----
  #pragma unroll
  for (int r = 0; r < 16; r++){
    int row = (r & 3) + 8*(r >> 2) + 4*hi;
    po[wave][row][ln]      = f2bf(o0[r]);
    po[wave][row][32 + ln] = f2bf(o1[r]);
  }
  if (hi == 0){ pmv[wave][ln] = m; plv[wave][ln] = l; }
  __syncthreads();

  // ---- flash-combine 4 partials; 256 threads cover 32 rows x 64 cols ----
  int t   = threadIdx.x;
  int row = t >> 3;
  int c8  = (t & 7) * 8;
  float m0 = pmv[0][row], m1 = pmv[1][row], m2 = pmv[2][row], m3 = pmv[3][row];
  float ms = fmaxf(fmaxf(m0, m1), fmaxf(m2, m3));
  float f0 = fexp2(m0 - ms), f1 = fexp2(m1 - ms);
  float f2 = fexp2(m2 - ms), f3 = fexp2(m3 - ms);
  float ls = plv[0][row]*f0 + plv[1][row]*f1 + plv[2][row]*f2 + plv[3][row]*f3;
  float inv = 1.0f / ls;
  f0 *= inv; f1 *= inv; f2 *= inv; f3 *= inv;
  int b = bh >> 4, h = bh & 15;
  u16 tmp[8];
  #pragma unroll
  for (int i = 0; i < 8; i += 4){
    ushort4 w0 = *reinterpret_cast<const ushort4*>(&po[0][row][c8 + i]);
    ushort4 w1 = *reinterpret_cast<const ushort4*>(&po[1][row][c8 + i]);
    ushort4 w2 = *reinterpret_cast<const ushort4*>(&po[2][row][c8 + i]);
    ushort4 w3 = *reinterpret_cast<const ushort4*>(&po[3][row][c8 + i]);
    const u16* p0 = (const u16*)&w0; const u16* p1 = (const u16*)&w1;
    const u16* p2 = (const u16*)&w2; const u16* p3 = (const u16*)&w3;
    #pragma unroll
    for (int j = 0; j < 4; j++){
      float v = __builtin_bit_cast(float, (unsigned)p0[j] << 16) * f0
              + __builtin_bit_cast(float, (unsigned)p1[j] << 16) * f1
              + __builtin_bit_cast(float, (unsigned)p2[j] << 16) * f2
              + __builtin_bit_cast(float, (unsigned)p3[j] << 16) * f3;
      tmp[i + j] = f2bf(v);
    }
  }
  u16* dst = vals + ((size_t)(b * SEQ + qw + row)) * EMBED + h * HD + c8;
  *reinterpret_cast<ushort4*>(dst)     = *reinterpret_cast<ushort4*>(&tmp[0]);
  *reinterpret_cast<ushort4*>(dst + 4) = *reinterpret_cast<ushort4*>(&tmp[4]);
}

// ---------------- GEMM2 (m97 structure): out = vals @ Wout + b ----------------
// 64x128 tile, BK=32, 4 waves (2x2), wave tile 32x64. Grid 512 blocks.
__global__ __launch_bounds__(256) void k_gemm_out(
    const u16* __restrict__ A, const u16* __restrict__ Bt,
    const float* __restrict__ bias, float* __restrict__ out)
{
  const int K = 1024;
  __shared__ __align__(16) u16 As[64*32];
  __shared__ __align__(16) u16 Bs[128*32];
  int t = threadIdx.x;
  int wave = t >> 6, lane = t & 63;
  int g = lane >> 4, c = lane & 15;
  int wr = wave >> 1, wc = wave & 1;
  int mb = blockIdx.y * 64, nb = blockIdx.x * 128;

  const u16* ga = A  + (size_t)(mb + wave*16 + (lane>>2)) * K + (lane&3)*8;
  const u16* gb = Bt + (size_t)(nb + wave*32 + (lane>>2)) * K + (lane&3)*8;
  u16* la = &As[wave*512];
  u16* lb = &Bs[wave*1024];

  f32x4 acc[2][4] = {};
  for (int k = 0; k < K; k += 32){
    gload16(ga + k,          la);
    gload16(gb + k,          lb);
    gload16(gb + k + 16*K,   lb + 512);
    __syncthreads();
    short8 af[2], bf[4];
    #pragma unroll
    for (int i = 0; i < 2; i++)
      af[i] = *reinterpret_cast<const short8*>(&As[(wr*32 + i*16 + c)*32 + 8*g]);
    #pragma unroll
    for (int j = 0; j < 4; j++)
      bf[j] = *reinterpret_cast<const short8*>(&Bs[(wc*64 + j*16 + c)*32 + 8*g]);
    #pragma unroll
    for (int i = 0; i < 2; i++)
      #pragma unroll
      for (int j = 0; j < 4; j++)
        acc[i][j] = __builtin_amdgcn_mfma_f32_16x16x32_bf16(af[i], bf[j], acc[i][j], 0, 0, 0);
    __syncthreads();
  }

  #pragma unroll
  for (int i = 0; i < 2; i++)
  #pragma unroll
  for (int j = 0; j < 4; j++)
  #pragma unroll
  for (int r = 0; r < 4; r++){
    int row = mb + wr*32 + i*16 + 4*g + r;
    int col = nb + wc*64 + j*16 + c;
    out[(size_t)row * EMBED + col] = acc[i][j][r] + bias[col];
  }
}

extern "C" void kernel_launch(void* const* d_in, const int* in_sizes, int n_in,
                              void* d_out, int out_size, void* d_ws, size_t ws_size,
                              hipStream_t stream){
  const float* x    = (const float*)d_in[0];
  const float* Wqkv = (const float*)d_in[1];
  const float* bqkv = (const float*)d_in[2];
  const float* Wout = (const float*)d_in[3];
  const float* bout = (const float*)d_in[4];
  float* out = (float*)d_out;

  char* ws = (char*)d_ws;
  u16* x_bf   = (u16*)(ws);                       // 8 MB
  u16* wqkv_t = (u16*)(ws + ( 8u << 20));         // 6 MB
  u16* wout_t = (u16*)(ws + (14u << 20));         // 2 MB
  u16* qbuf   = (u16*)(ws + (16u << 20));         // 8 MB (fragment order)
  u16* kbuf   = (u16*)(ws + (24u << 20));         // 8 MB (fragment order)
  u16* vtbuf  = (u16*)(ws + (32u << 20));         // 8 MB (fragment order)
  u16* vals   = (u16*)(ws + (40u << 20));         // 8 MB   (48 MB total)

  k_cvt<<<4096, 256, 0, stream>>>(x, x_bf);
  dim3 tb(32, 8);
  k_transpose<<<dim3(3072/32, 1024/32), tb, 0, stream>>>(Wqkv, wqkv_t, 1024, 3072);
  k_transpose<<<dim3(1024/32, 1024/32), tb, 0, stream>>>(Wout, wout_t, 1024, 1024);
  k_gemm_qkv<<<dim3(3072/128, 4096/128), 256, 0, stream>>>(x_bf, wqkv_t, bqkv, qbuf, kbuf, vtbuf);
  k_attn<<<2048, 256, 0, stream>>>(qbuf, kbuf, vtbuf, vals);
  k_gemm_out<<<dim3(1024/128, 4096/64), 256, 0, stream>>>(vals, wout_t, bout, out);
}